// Round 1
// baseline (391.043 us; speedup 1.0000x reference)
//
#include <hip/hip_runtime.h>

#define EPSV 1e-5f

typedef __bf16 bf16x8 __attribute__((ext_vector_type(8)));
typedef float f32x4 __attribute__((ext_vector_type(4)));
typedef unsigned short ushort8 __attribute__((ext_vector_type(8)));

__device__ __forceinline__ void gload16(const void* g, void* l) {
  __builtin_amdgcn_global_load_lds(
      (const __attribute__((address_space(1))) unsigned int*)g,
      (__attribute__((address_space(3))) unsigned int*)l, 16, 0, 0);
}

// ---------------- K0: weight fragments + folded bias ----------------
// B-fragment layout for mfma_f32_16x16x32_bf16:
//   element (tap, half, lane, j) = w'[co = half*16 + (lane&15)][ci = (lane>>4)*8 + j][tap]
// flat index = ((tap*2 + half)*64 + lane)*8 + j
__global__ __launch_bounds__(256) void prep_weights(
    const float* __restrict__ w1, const float* __restrict__ b1,
    const float* __restrict__ g2, const float* __restrict__ be2,
    const float* __restrict__ m2, const float* __restrict__ v2,
    const float* __restrict__ w2,
    __bf16* __restrict__ wf1, __bf16* __restrict__ wf2,
    float* __restrict__ bias1p) {
  int i = blockIdx.x * 256 + threadIdx.x;   // 0..18431
  int conv = i / 9216;
  int rem  = i % 9216;
  int tap  = rem >> 10;          // 0..8
  int r2   = rem & 1023;
  int half = r2 >> 9;
  int lane = (r2 >> 3) & 63;
  int j    = r2 & 7;
  int ci = ((lane >> 4) << 3) + j;
  int co = half * 16 + (lane & 15);
  float val = (conv ? w2 : w1)[(co * 32 + ci) * 9 + tap];
  if (!conv) val *= g2[co] * rsqrtf(v2[co] + EPSV);   // fold BN2 scale into w1
  (conv ? wf2 : wf1)[rem] = (__bf16)val;
  if (blockIdx.x == 0 && threadIdx.x < 32) {
    int c = threadIdx.x;
    float s2 = g2[c] * rsqrtf(v2[c] + EPSV);
    bias1p[c] = s2 * b1[c] + (be2[c] - m2[c] * s2);   // scale2*b1 + shift2
  }
}

// ---------------- K1: BN1+ReLU + NCHW -> swizzled NHWC bf16 ----------------
// xb row layout (per global pixel w of a row): 4 chunks of 8 bf16; channel-chunk cb
// stored at slot s = cb ^ ((w>>1)&3)  (bank-spreads later ds_read_b128 A-fragments)
__global__ __launch_bounds__(256) void bn_relu_pack(
    const float* __restrict__ x,
    const float* __restrict__ g1, const float* __restrict__ be1,
    const float* __restrict__ m1, const float* __restrict__ v1,
    unsigned short* __restrict__ xb) {
  __shared__ __align__(16) unsigned short sh[128 * 40];
  int t = threadIdx.x;
  int b = blockIdx.x >> 7, h = blockIdx.x & 127;
  int c = t >> 3, w0 = (t & 7) * 16;
  float sc = g1[c] * rsqrtf(v1[c] + EPSV);
  float sf = be1[c] - m1[c] * sc;
  const float* src = x + (((long)(b * 32 + c) * 128 + h) * 128 + w0);
  #pragma unroll
  for (int k = 0; k < 16; k += 4) {
    f32x4 v = *reinterpret_cast<const f32x4*>(src + k);
    #pragma unroll
    for (int q = 0; q < 4; q++) {
      float val = fmaxf(v[q] * sc + sf, 0.0f);
      sh[(w0 + k + q) * 40 + c] = __builtin_bit_cast(unsigned short, (__bf16)val);
    }
  }
  __syncthreads();
  int pix = t >> 1, hh = t & 1;
  int q2 = (pix >> 1) & 3;
  unsigned short* dst = xb + (long)blockIdx.x * (128 * 32);
  #pragma unroll
  for (int cc = 0; cc < 2; cc++) {
    int cb = 2 * hh + cc;
    int s = cb ^ q2;
    ushort8 vv = *reinterpret_cast<const ushort8*>(&sh[pix * 40 + cb * 8]);
    *reinterpret_cast<ushort8*>(dst + (pix * 4 + s) * 8) = vv;
  }
}

// ---------------- K2/K3: 3x3 conv via per-tap MFMA GEMMs ----------------
// PASS 1: in=xb -> relu(conv*w1' + bias1p) -> hb (swizzled NHWC bf16)
// PASS 2: in=hb -> conv*w2 + b2 + x       -> out (NCHW fp32)
// block = 256 thr (4 waves); block handles 8-row strip of one image.
// LDS ring of 4 row-slots [130 px][4 chunk][16B], staged with global_load_lds(16B).
template <int PASS>
__global__ __launch_bounds__(256) void conv3x3(
    const unsigned short* __restrict__ in,
    const __bf16* __restrict__ wfrag,
    const float* __restrict__ bias,
    const float* __restrict__ xres,
    unsigned short* __restrict__ outb,
    float* __restrict__ outf) {
  __shared__ __align__(16) unsigned short tile[4 * 130 * 32];  // 33280 B
  __shared__ __align__(16) float epi[32 * 129];                // 16512 B (PASS1: ushort[128][40])
  int t = threadIdx.x;
  int lane = t & 63, wv = t >> 6;
  int b = blockIdx.x >> 4;
  int h0 = (blockIdx.x & 15) * 8;

  // weights -> registers (72 VGPRs)
  bf16x8 Bf[9][2];
  #pragma unroll
  for (int tap = 0; tap < 9; tap++)
    #pragma unroll
    for (int hf = 0; hf < 2; hf++)
      Bf[tap][hf] = reinterpret_cast<const bf16x8*>(wfrag)[(tap * 2 + hf) * 64 + lane];
  float bco[2] = { bias[lane & 15], bias[16 + (lane & 15)] };

  // per-lane A-fragment byte offsets within a row slot, for (group, dx)
  int cb = lane >> 4;
  int offs[2][3];
  #pragma unroll
  for (int g = 0; g < 2; g++)
    #pragma unroll
    for (int dx = 0; dx < 3; dx++) {
      int w = wv * 32 + g * 16 + (lane & 15) + dx - 1;  // -1..128
      int s = cb ^ ((w >> 1) & 3);
      offs[g][dx] = (w + 1) * 64 + s * 16;
    }

  auto stage_row = [&](int rho) {
    int slot = (rho + 4) & 3;
    unsigned short* base = &tile[slot * (130 * 32)];
    int hr = h0 + rho;
    if (hr < 0 || hr >= 128) {                // out-of-image row: zero slot
      ushort8 z{};
      for (int k = t; k < 520; k += 256)
        *reinterpret_cast<ushort8*>(base + k * 8) = z;
    } else {
      if (t < 8) {                            // zero pad columns wp=0, wp=129
        ushort8 z{};
        int k = (t < 4) ? t : (512 + t);
        *reinterpret_cast<ushort8*>(base + k * 8) = z;
      }
      const char* src = reinterpret_cast<const char*>(in) +
                        ((long)(b * 128 + hr) * 128) * 64;
      #pragma unroll
      for (int i = 0; i < 2; i++) {
        int kb = wv * 128 + i * 64;           // wave-uniform
        gload16(src + (long)(kb + lane) * 16,
                reinterpret_cast<char*>(base) + 64 + kb * 16);
      }
    }
  };

  stage_row(-1); stage_row(0); stage_row(1);
  __syncthreads();   // drains vmcnt (gload_lds) + lgkmcnt

  for (int r = 0; r < 8; r++) {
    if (r + 2 <= 8) stage_row(r + 2);         // prefetch, hidden under compute
    int hr = h0 + r;
    f32x4 acc[2][2] = {};
    #pragma unroll
    for (int dy = 0; dy < 3; dy++) {
      char* rowbase = reinterpret_cast<char*>(&tile[((r + 3 + dy) & 3) * (130 * 32)]);
      #pragma unroll
      for (int dx = 0; dx < 3; dx++) {
        #pragma unroll
        for (int g = 0; g < 2; g++) {
          bf16x8 a = *reinterpret_cast<const bf16x8*>(rowbase + offs[g][dx]);
          acc[g][0] = __builtin_amdgcn_mfma_f32_16x16x32_bf16(a, Bf[dy * 3 + dx][0], acc[g][0], 0, 0, 0);
          acc[g][1] = __builtin_amdgcn_mfma_f32_16x16x32_bf16(a, Bf[dy * 3 + dx][1], acc[g][1], 0, 0, 0);
        }
      }
    }
    if (PASS == 1) {
      unsigned short* eb = reinterpret_cast<unsigned short*>(epi);  // [128][40]
      #pragma unroll
      for (int g = 0; g < 2; g++)
        #pragma unroll
        for (int hf = 0; hf < 2; hf++) {
          int co = hf * 16 + (lane & 15);
          #pragma unroll
          for (int j = 0; j < 4; j++) {
            int pix = wv * 32 + g * 16 + ((lane >> 4) << 2) + j;
            float val = fmaxf(acc[g][hf][j] + bco[hf], 0.0f);
            eb[pix * 40 + co] = __builtin_bit_cast(unsigned short, (__bf16)val);
          }
        }
      __syncthreads();
      int pix = t >> 1, hh = t & 1;
      int q2 = (pix >> 1) & 3;
      unsigned short* dst = outb + ((long)(b * 128 + hr) * 128) * 32;
      #pragma unroll
      for (int cc = 0; cc < 2; cc++) {
        int cbo = 2 * hh + cc;
        int s = cbo ^ q2;
        ushort8 vv = *reinterpret_cast<const ushort8*>(&eb[pix * 40 + cbo * 8]);
        *reinterpret_cast<ushort8*>(dst + (pix * 4 + s) * 8) = vv;
      }
    } else {
      #pragma unroll
      for (int g = 0; g < 2; g++)
        #pragma unroll
        for (int hf = 0; hf < 2; hf++) {
          int co = hf * 16 + (lane & 15);
          int pix0 = wv * 32 + g * 16 + ((lane >> 4) << 2);
          f32x4 xr = *reinterpret_cast<const f32x4*>(
              xres + (((long)(b * 32 + co) * 128 + hr) * 128 + pix0));
          #pragma unroll
          for (int j = 0; j < 4; j++)
            epi[co * 129 + pix0 + j] = acc[g][hf][j] + bco[hf] + xr[j];
        }
      __syncthreads();
      int co = t >> 3, p0 = (t & 7) * 16;
      float* dst = outf + (((long)(b * 32 + co) * 128 + hr) * 128 + p0);
      #pragma unroll
      for (int k = 0; k < 16; k += 4) {
        f32x4 vv;
        #pragma unroll
        for (int q = 0; q < 4; q++) vv[q] = epi[co * 129 + p0 + k + q];
        *reinterpret_cast<f32x4*>(dst + k) = vv;
      }
    }
    __syncthreads();   // epi reuse fence + drains prefetch vmcnt before next row
  }
}

extern "C" void kernel_launch(void* const* d_in, const int* in_sizes, int n_in,
                              void* d_out, int out_size, void* d_ws, size_t ws_size,
                              hipStream_t stream) {
  const float* x   = (const float*)d_in[0];
  const float* g1  = (const float*)d_in[1];
  const float* be1 = (const float*)d_in[2];
  const float* m1  = (const float*)d_in[3];
  const float* v1  = (const float*)d_in[4];
  const float* w1  = (const float*)d_in[5];
  const float* b1  = (const float*)d_in[6];
  const float* g2  = (const float*)d_in[7];
  const float* be2 = (const float*)d_in[8];
  const float* m2  = (const float*)d_in[9];
  const float* v2  = (const float*)d_in[10];
  const float* w2  = (const float*)d_in[11];
  const float* b2  = (const float*)d_in[12];

  char* ws = (char*)d_ws;
  unsigned short* xb = (unsigned short*)ws;                       // 64 MiB
  unsigned short* hb = (unsigned short*)(ws + 67108864);          // 64 MiB
  __bf16* wf1   = (__bf16*)(ws + 134217728);                      // 18432 B
  __bf16* wf2   = (__bf16*)(ws + 134217728 + 18432);              // 18432 B
  float*  bias1p = (float*)(ws + 134217728 + 36864);              // 128 B

  prep_weights<<<dim3(72), dim3(256), 0, stream>>>(w1, b1, g2, be2, m2, v2, w2, wf1, wf2, bias1p);
  bn_relu_pack<<<dim3(8192), dim3(256), 0, stream>>>(x, g1, be1, m1, v1, xb);
  conv3x3<1><<<dim3(1024), dim3(256), 0, stream>>>(xb, wf1, bias1p, nullptr, hb, nullptr);
  conv3x3<2><<<dim3(1024), dim3(256), 0, stream>>>(hb, wf2, b2, x, nullptr, (float*)d_out);
}

// Round 3
// 362.311 us; speedup vs baseline: 1.0793x; 1.0793x over previous
//
#include <hip/hip_runtime.h>

#define EPSV 1e-5f

typedef __bf16 bf16x8 __attribute__((ext_vector_type(8)));
typedef float f32x4 __attribute__((ext_vector_type(4)));
typedef unsigned short ushort8 __attribute__((ext_vector_type(8)));

__device__ __forceinline__ void gload16(const void* g, void* l) {
  __builtin_amdgcn_global_load_lds(
      (const __attribute__((address_space(1))) unsigned int*)g,
      (__attribute__((address_space(3))) unsigned int*)l, 16, 0, 0);
}

// ---------------- K0: weight fragments + folded bias ----------------
// B-fragment layout for mfma_f32_16x16x32_bf16:
//   element (tap, half, lane, j) = w'[co = half*16 + (lane&15)][ci = (lane>>4)*8 + j][tap]
__global__ __launch_bounds__(256) void prep_weights(
    const float* __restrict__ w1, const float* __restrict__ b1,
    const float* __restrict__ g2, const float* __restrict__ be2,
    const float* __restrict__ m2, const float* __restrict__ v2,
    const float* __restrict__ w2,
    __bf16* __restrict__ wf1, __bf16* __restrict__ wf2,
    float* __restrict__ bias1p) {
  int i = blockIdx.x * 256 + threadIdx.x;   // 0..18431
  int conv = i / 9216;
  int rem  = i % 9216;
  int tap  = rem >> 10;          // 0..8
  int r2   = rem & 1023;
  int half = r2 >> 9;
  int lane = (r2 >> 3) & 63;
  int j    = r2 & 7;
  int ci = ((lane >> 4) << 3) + j;
  int co = half * 16 + (lane & 15);
  float val = (conv ? w2 : w1)[(co * 32 + ci) * 9 + tap];
  if (!conv) val *= g2[co] * rsqrtf(v2[co] + EPSV);   // fold BN2 scale into w1
  (conv ? wf2 : wf1)[rem] = (__bf16)val;
  if (blockIdx.x == 0 && threadIdx.x < 32) {
    int c = threadIdx.x;
    float s2 = g2[c] * rsqrtf(v2[c] + EPSV);
    bias1p[c] = s2 * b1[c] + (be2[c] - m2[c] * s2);   // scale2*b1 + shift2
  }
}

// ---------------- K1: BN1+ReLU + NCHW -> swizzled NHWC bf16 ----------------
// xb row layout (per global pixel w of a row): 4 chunks of 8 bf16; channel-chunk cb
// stored at slot s = cb ^ ((w>>1)&3)
__global__ __launch_bounds__(256) void bn_relu_pack(
    const float* __restrict__ x,
    const float* __restrict__ g1, const float* __restrict__ be1,
    const float* __restrict__ m1, const float* __restrict__ v1,
    unsigned short* __restrict__ xb) {
  __shared__ __align__(16) unsigned short sh[128 * 40];
  int t = threadIdx.x;
  int b = blockIdx.x >> 7, h = blockIdx.x & 127;
  int c = t >> 3, w0 = (t & 7) * 16;
  float sc = g1[c] * rsqrtf(v1[c] + EPSV);
  float sf = be1[c] - m1[c] * sc;
  const float* src = x + (((long)(b * 32 + c) * 128 + h) * 128 + w0);
  #pragma unroll
  for (int k = 0; k < 16; k += 4) {
    f32x4 v = *reinterpret_cast<const f32x4*>(src + k);
    #pragma unroll
    for (int q = 0; q < 4; q++) {
      float val = fmaxf(v[q] * sc + sf, 0.0f);
      sh[(w0 + k + q) * 40 + c] = __builtin_bit_cast(unsigned short, (__bf16)val);
    }
  }
  __syncthreads();
  int pix = t >> 1, hh = t & 1;
  int q2 = (pix >> 1) & 3;
  unsigned short* dst = xb + (long)blockIdx.x * (128 * 32);
  #pragma unroll
  for (int cc = 0; cc < 2; cc++) {
    int cb = 2 * hh + cc;
    int s = cb ^ q2;
    ushort8 vv = *reinterpret_cast<const ushort8*>(&sh[pix * 40 + cb * 8]);
    *reinterpret_cast<ushort8*>(dst + (pix * 4 + s) * 8) = vv;
  }
}

// ---------------- K2/K3: 3x3 conv via per-tap MFMA GEMMs ----------------
// 4-row output strips, all 6 input rows staged upfront (no ring, 1 stage barrier).
// PASS 1: in=xb -> relu(conv*w1' + bias1p) -> hb   (reg-held acc, LDS repack, 3 barriers)
// PASS 2: in=hb -> conv*w2 + b2 + x -> out (NCHW fp32), direct stores, 1 barrier
template <int PASS>
__global__ __launch_bounds__(256, PASS == 1 ? 2 : 3) void conv3x3(
    const unsigned short* __restrict__ in,
    const __bf16* __restrict__ wfrag,
    const float* __restrict__ bias,
    const float* __restrict__ xres,
    unsigned short* __restrict__ outb,
    float* __restrict__ outf) {
  __shared__ __align__(16) unsigned short tile[6 * 4160];  // 6 slots x 130px x 32ch = 49920 B
  int t = threadIdx.x;
  int lane = t & 63, wv = t >> 6;
  int b = blockIdx.x >> 5;
  int h0 = (blockIdx.x & 31) * 4;

  // weights -> registers (72 VGPRs)
  bf16x8 Bf[9][2];
  #pragma unroll
  for (int tap = 0; tap < 9; tap++)
    #pragma unroll
    for (int hf = 0; hf < 2; hf++)
      Bf[tap][hf] = reinterpret_cast<const bf16x8*>(wfrag)[(tap * 2 + hf) * 64 + lane];
  float bco[2] = { bias[lane & 15], bias[16 + (lane & 15)] };

  // per-lane A-fragment byte offsets within a row slot, for (group, dx)
  int cb = lane >> 4;
  int offs[2][3];
  #pragma unroll
  for (int g = 0; g < 2; g++)
    #pragma unroll
    for (int dx = 0; dx < 3; dx++) {
      int w = wv * 32 + g * 16 + (lane & 15) + dx - 1;  // -1..128
      int s = cb ^ ((w >> 1) & 3);
      offs[g][dx] = (w + 1) * 64 + s * 16;
    }

  // ---- stage all 6 input rows (h0-1 .. h0+4) ----
  #pragma unroll
  for (int rr = 0; rr < 6; rr++) {
    int hr = h0 - 1 + rr;
    unsigned short* base = &tile[rr * 4160];
    if (hr < 0 || hr >= 128) {
      ushort8 z{};
      for (int k = t; k < 520; k += 256)
        *reinterpret_cast<ushort8*>(base + k * 8) = z;
    } else {
      const char* src = reinterpret_cast<const char*>(in) +
                        ((long)(b * 128 + hr) * 128) * 64;
      #pragma unroll
      for (int i = 0; i < 2; i++) {
        int kb = (wv * 2 + i) * 64;           // wave-uniform
        gload16(src + (long)(kb + lane) * 16,
                reinterpret_cast<char*>(base) + 64 + kb * 16);
      }
    }
  }
  if (t < 48) {   // zero pad columns w=-1 and w=128 for all 6 slots
    int sl = t >> 3, r2 = t & 7;
    int phys = (r2 >> 2) * 129, ch = r2 & 3;
    *reinterpret_cast<ushort8*>(&tile[sl * 4160 + phys * 32 + ch * 8]) = ushort8{};
  }
  __syncthreads();   // drains gload_lds vmcnt + lgkmcnt

  f32x4 acc4[4][2][2] = {};   // PASS1 keeps all 4 rows; PASS2 uses row slice then stores
  #pragma unroll
  for (int r = 0; r < 4; r++) {
    #pragma unroll
    for (int dy = 0; dy < 3; dy++) {
      const char* rowbase = reinterpret_cast<const char*>(&tile[(r + dy) * 4160]);
      #pragma unroll
      for (int dx = 0; dx < 3; dx++) {
        #pragma unroll
        for (int g = 0; g < 2; g++) {
          bf16x8 a = *reinterpret_cast<const bf16x8*>(rowbase + offs[g][dx]);
          acc4[r][g][0] = __builtin_amdgcn_mfma_f32_16x16x32_bf16(a, Bf[dy * 3 + dx][0], acc4[r][g][0], 0, 0, 0);
          acc4[r][g][1] = __builtin_amdgcn_mfma_f32_16x16x32_bf16(a, Bf[dy * 3 + dx][1], acc4[r][g][1], 0, 0, 0);
        }
      }
    }
    if (PASS == 2) {
      int hr = h0 + r;
      #pragma unroll
      for (int g = 0; g < 2; g++)
        #pragma unroll
        for (int hf = 0; hf < 2; hf++) {
          int co = hf * 16 + (lane & 15);
          int pix0 = wv * 32 + g * 16 + ((lane >> 4) << 2);
          long idx = ((long)(b * 32 + co) * 128 + hr) * 128 + pix0;
          f32x4 xr = *reinterpret_cast<const f32x4*>(xres + idx);
          f32x4 o;
          #pragma unroll
          for (int j = 0; j < 4; j++) o[j] = acc4[r][g][hf][j] + bco[hf] + xr[j];
          *reinterpret_cast<f32x4*>(outf + idx) = o;
        }
    }
  }

  if (PASS == 1) {
    __syncthreads();   // tile staging now dead; reuse as repack buffer
    #pragma unroll
    for (int r = 0; r < 4; r++)
      #pragma unroll
      for (int g = 0; g < 2; g++)
        #pragma unroll
        for (int hf = 0; hf < 2; hf++) {
          int co = hf * 16 + (lane & 15);
          #pragma unroll
          for (int j = 0; j < 4; j++) {
            int pix = wv * 32 + g * 16 + ((lane >> 4) << 2) + j;
            float val = fmaxf(acc4[r][g][hf][j] + bco[hf], 0.0f);
            int byte = r * 8192 + pix * 64 + (((co >> 3) ^ ((pix >> 1) & 3)) << 4) + (co & 7) * 2;
            *reinterpret_cast<unsigned short*>(reinterpret_cast<char*>(tile) + byte) =
                __builtin_bit_cast(unsigned short, (__bf16)val);
          }
        }
    __syncthreads();
    unsigned short* dst = outb + ((long)(b * 128 + h0) * 128) * 32;   // 4 rows contiguous
    #pragma unroll
    for (int i = 0; i < 8; i++) {
      int u = i * 256 + t;
      *reinterpret_cast<ushort8*>(dst + u * 8) =
          *reinterpret_cast<const ushort8*>(reinterpret_cast<const char*>(tile) + u * 16);
    }
  }
}

extern "C" void kernel_launch(void* const* d_in, const int* in_sizes, int n_in,
                              void* d_out, int out_size, void* d_ws, size_t ws_size,
                              hipStream_t stream) {
  const float* x   = (const float*)d_in[0];
  const float* g1  = (const float*)d_in[1];
  const float* be1 = (const float*)d_in[2];
  const float* m1  = (const float*)d_in[3];
  const float* v1  = (const float*)d_in[4];
  const float* w1  = (const float*)d_in[5];
  const float* b1  = (const float*)d_in[6];
  const float* g2  = (const float*)d_in[7];
  const float* be2 = (const float*)d_in[8];
  const float* m2  = (const float*)d_in[9];
  const float* v2  = (const float*)d_in[10];
  const float* w2  = (const float*)d_in[11];
  const float* b2  = (const float*)d_in[12];

  char* ws = (char*)d_ws;
  unsigned short* xb = (unsigned short*)ws;                       // 64 MiB
  unsigned short* hb = (unsigned short*)(ws + 67108864);          // 64 MiB
  __bf16* wf1   = (__bf16*)(ws + 134217728);                      // 18432 B
  __bf16* wf2   = (__bf16*)(ws + 134217728 + 18432);              // 18432 B
  float*  bias1p = (float*)(ws + 134217728 + 36864);              // 128 B

  prep_weights<<<dim3(72), dim3(256), 0, stream>>>(w1, b1, g2, be2, m2, v2, w2, wf1, wf2, bias1p);
  bn_relu_pack<<<dim3(8192), dim3(256), 0, stream>>>(x, g1, be1, m1, v1, xb);
  conv3x3<1><<<dim3(2048), dim3(256), 0, stream>>>(xb, wf1, bias1p, nullptr, hb, nullptr);
  conv3x3<2><<<dim3(2048), dim3(256), 0, stream>>>(hb, wf2, b2, x, nullptr, (float*)d_out);
}

// Round 4
// 326.671 us; speedup vs baseline: 1.1971x; 1.1091x over previous
//
#include <hip/hip_runtime.h>

#define EPSV 1e-5f

typedef __bf16 bf16x8 __attribute__((ext_vector_type(8)));
typedef float f32x4 __attribute__((ext_vector_type(4)));
typedef float f32x2 __attribute__((ext_vector_type(2)));
typedef unsigned short ushort8 __attribute__((ext_vector_type(8)));

// ---------------- K0: weight fragments + folded biases + BN1 coeffs ----------------
// B-fragment layout for mfma_f32_16x16x32_bf16:
//   element (tap, half, lane, j) = w'[co = half*16 + (lane&15)][ci = (lane>>4)*8 + j][tap]
__global__ __launch_bounds__(256) void prep_weights(
    const float* __restrict__ w1, const float* __restrict__ b1,
    const float* __restrict__ g2, const float* __restrict__ be2,
    const float* __restrict__ m2, const float* __restrict__ v2,
    const float* __restrict__ w2,
    const float* __restrict__ g1, const float* __restrict__ be1,
    const float* __restrict__ m1, const float* __restrict__ v1,
    __bf16* __restrict__ wf1, __bf16* __restrict__ wf2,
    float* __restrict__ bias1p, float* __restrict__ sc1, float* __restrict__ sf1) {
  int i = blockIdx.x * 256 + threadIdx.x;   // 0..18431
  int conv = i / 9216;
  int rem  = i % 9216;
  int tap  = rem >> 10;          // 0..8
  int r2   = rem & 1023;
  int half = r2 >> 9;
  int lane = (r2 >> 3) & 63;
  int j    = r2 & 7;
  int ci = ((lane >> 4) << 3) + j;
  int co = half * 16 + (lane & 15);
  float val = (conv ? w2 : w1)[(co * 32 + ci) * 9 + tap];
  if (!conv) val *= g2[co] * rsqrtf(v2[co] + EPSV);   // fold BN2 scale into w1
  (conv ? wf2 : wf1)[rem] = (__bf16)val;
  if (blockIdx.x == 0 && threadIdx.x < 32) {
    int c = threadIdx.x;
    float s2 = g2[c] * rsqrtf(v2[c] + EPSV);
    bias1p[c] = s2 * b1[c] + (be2[c] - m2[c] * s2);   // scale2*b1 + shift2
  }
  if (blockIdx.x == 0 && threadIdx.x >= 64 && threadIdx.x < 96) {
    int c = threadIdx.x - 64;
    float s = g1[c] * rsqrtf(v1[c] + EPSV);
    sc1[c] = s;
    sf1[c] = be1[c] - m1[c] * s;
  }
}

// ---------------- K1: fused BN1+ReLU+conv1 -> hb (swizzled NHWC bf16) ----------------
// Block = 4-row output strip. Stage rows h0-1..h0+4 of x directly (fp32 NCHW),
// BN1+ReLU in regs, transpose via ds_write_b128 of one swizzled 8-ch chunk per pixel.
// tile layout per slot: [130 px][32 ch], chunk slot s = (ch>>3) ^ ((px>>1)&3), px stored at px+1.
__global__ __launch_bounds__(256, 2) void bnconv1(
    const float* __restrict__ x,
    const float* __restrict__ sc1, const float* __restrict__ sf1,
    const __bf16* __restrict__ wfrag, const float* __restrict__ bias,
    unsigned short* __restrict__ outb) {
  __shared__ __align__(16) unsigned short tile[6 * 4160];  // 49920 B
  char* tb = reinterpret_cast<char*>(tile);
  int t = threadIdx.x, lane = t & 63, wv = t >> 6;
  int Bw = blockIdx.x;
  int logical = (Bw & 7) * 256 + (Bw >> 3);   // XCD-contiguous strips
  int b = logical >> 5, h0 = (logical & 31) * 4;

  // BN1 coeffs for this wave's channel chunk (wave-uniform)
  float sc[8], sf[8];
  #pragma unroll
  for (int cc = 0; cc < 8; cc++) { sc[cc] = sc1[wv * 8 + cc]; sf[cc] = sf1[wv * 8 + cc]; }

  // ---- stage: wave wv produces chunk cb=wv for all 6 slots ----
  int wbyte0 = (2 * lane + 1) * 64 + ((wv ^ (lane & 3)) << 4);
  #pragma unroll
  for (int k = 0; k < 6; k++) {
    int hr = h0 - 1 + k;
    char* dst = tb + k * 8320 + wbyte0;
    if (hr >= 0 && hr < 128) {
      const float* src = x + (long)(b * 32 + wv * 8) * 16384 + hr * 128 + 2 * lane;
      float p0[8], p1[8];
      #pragma unroll
      for (int cc = 0; cc < 8; cc++) {
        f32x2 v = *reinterpret_cast<const f32x2*>(src + cc * 16384);
        p0[cc] = fmaxf(fmaf(v[0], sc[cc], sf[cc]), 0.0f);
        p1[cc] = fmaxf(fmaf(v[1], sc[cc], sf[cc]), 0.0f);
      }
      bf16x8 a0, a1;
      #pragma unroll
      for (int cc = 0; cc < 8; cc++) { a0[cc] = (__bf16)p0[cc]; a1[cc] = (__bf16)p1[cc]; }
      *reinterpret_cast<bf16x8*>(dst) = a0;
      *reinterpret_cast<bf16x8*>(dst + 64) = a1;
    } else {
      *reinterpret_cast<bf16x8*>(dst) = bf16x8{};
      *reinterpret_cast<bf16x8*>(dst + 64) = bf16x8{};
    }
  }
  if (t < 48) {   // zero pad columns px=-1 and px=128 for all 6 slots
    int sl = t >> 3, r2 = t & 7;
    int phys = (r2 >> 2) * 129, ch = r2 & 3;
    *reinterpret_cast<ushort8*>(&tile[sl * 4160 + phys * 32 + ch * 8]) = ushort8{};
  }

  // weights -> registers (overlaps with LDS-write drain)
  bf16x8 Bf[9][2];
  #pragma unroll
  for (int tap = 0; tap < 9; tap++)
    #pragma unroll
    for (int hf = 0; hf < 2; hf++)
      Bf[tap][hf] = reinterpret_cast<const bf16x8*>(wfrag)[(tap * 2 + hf) * 64 + lane];
  float bco[2] = { bias[lane & 15], bias[16 + (lane & 15)] };

  // per-lane A-fragment byte offsets within a slot
  int cb = lane >> 4;
  int offs[2][3];
  #pragma unroll
  for (int g = 0; g < 2; g++)
    #pragma unroll
    for (int dx = 0; dx < 3; dx++) {
      int w = wv * 32 + g * 16 + (lane & 15) + dx - 1;  // -1..128
      int s = cb ^ ((w >> 1) & 3);
      offs[g][dx] = (w + 1) * 64 + s * 16;
    }

  __syncthreads();

  f32x4 acc4[4][2][2] = {};
  #pragma unroll
  for (int r = 0; r < 4; r++)
    #pragma unroll
    for (int dy = 0; dy < 3; dy++) {
      const char* rowbase = tb + (r + dy) * 8320;
      #pragma unroll
      for (int dx = 0; dx < 3; dx++)
        #pragma unroll
        for (int g = 0; g < 2; g++) {
          bf16x8 a = *reinterpret_cast<const bf16x8*>(rowbase + offs[g][dx]);
          acc4[r][g][0] = __builtin_amdgcn_mfma_f32_16x16x32_bf16(a, Bf[dy * 3 + dx][0], acc4[r][g][0], 0, 0, 0);
          acc4[r][g][1] = __builtin_amdgcn_mfma_f32_16x16x32_bf16(a, Bf[dy * 3 + dx][1], acc4[r][g][1], 0, 0, 0);
        }
    }

  __syncthreads();   // staging tile now dead; reuse as repack buffer
  #pragma unroll
  for (int r = 0; r < 4; r++)
    #pragma unroll
    for (int g = 0; g < 2; g++)
      #pragma unroll
      for (int hf = 0; hf < 2; hf++) {
        int co = hf * 16 + (lane & 15);
        #pragma unroll
        for (int j = 0; j < 4; j++) {
          int pix = wv * 32 + g * 16 + ((lane >> 4) << 2) + j;
          float val = fmaxf(acc4[r][g][hf][j] + bco[hf], 0.0f);
          int byte = r * 8192 + pix * 64 + (((co >> 3) ^ ((pix >> 1) & 3)) << 4) + (co & 7) * 2;
          *reinterpret_cast<unsigned short*>(tb + byte) =
              __builtin_bit_cast(unsigned short, (__bf16)val);
        }
      }
  __syncthreads();
  unsigned short* dst = outb + ((long)(b * 128 + h0) * 128) * 32;   // 4 rows contiguous
  #pragma unroll
  for (int i = 0; i < 8; i++) {
    int u = i * 256 + t;
    *reinterpret_cast<ushort8*>(dst + u * 8) =
        *reinterpret_cast<const ushort8*>(tb + u * 16);
  }
}

// ---------------- K2: conv2 LDS-free — A-fragments direct from L2 ----------------
// out = conv(hb, w2) + b2 + x, NCHW fp32. No LDS, no barriers.
__global__ __launch_bounds__(256, 2) void conv2_direct(
    const unsigned short* __restrict__ hb,
    const __bf16* __restrict__ wfrag, const float* __restrict__ bias,
    const float* __restrict__ xres, float* __restrict__ outf) {
  int t = threadIdx.x, lane = t & 63, wv = t >> 6;
  int Bw = blockIdx.x;
  int logical = (Bw & 7) * 256 + (Bw >> 3);
  int b = logical >> 5, h0 = (logical & 31) * 4;

  bf16x8 Bf[9][2];
  #pragma unroll
  for (int tap = 0; tap < 9; tap++)
    #pragma unroll
    for (int hf = 0; hf < 2; hf++)
      Bf[tap][hf] = reinterpret_cast<const bf16x8*>(wfrag)[(tap * 2 + hf) * 64 + lane];
  float bco[2] = { bias[lane & 15], bias[16 + (lane & 15)] };

  // per-lane column byte offsets (clamped in-bounds) + edge masks
  int cb = lane >> 4;
  int coloff[2][3];
  bool colbad[2][3];
  #pragma unroll
  for (int g = 0; g < 2; g++)
    #pragma unroll
    for (int dx = 0; dx < 3; dx++) {
      int w = wv * 32 + g * 16 + (lane & 15) + dx - 1;  // -1..128
      colbad[g][dx] = (w < 0) || (w > 127);
      int wc = w < 0 ? 0 : (w > 127 ? 127 : w);
      int s = cb ^ ((wc >> 1) & 3);
      coloff[g][dx] = wc * 64 + s * 16;
    }

  const char* hbase = reinterpret_cast<const char*>(hb) + (long)b * 128 * 8192;

  #pragma unroll
  for (int r = 0; r < 4; r++) {
    f32x4 acc[2][2] = {};
    #pragma unroll
    for (int dy = 0; dy < 3; dy++) {
      int hr_in = h0 + r + dy - 1;
      if (hr_in >= 0 && hr_in < 128) {      // uniform branch; pad rows contribute 0
        const char* rowb = hbase + (long)hr_in * 8192;
        #pragma unroll
        for (int dx = 0; dx < 3; dx++)
          #pragma unroll
          for (int g = 0; g < 2; g++) {
            bf16x8 a = *reinterpret_cast<const bf16x8*>(rowb + coloff[g][dx]);
            if (colbad[g][dx]) a = bf16x8{};   // per-lane select -> 0 at image edge
            acc[g][0] = __builtin_amdgcn_mfma_f32_16x16x32_bf16(a, Bf[dy * 3 + dx][0], acc[g][0], 0, 0, 0);
            acc[g][1] = __builtin_amdgcn_mfma_f32_16x16x32_bf16(a, Bf[dy * 3 + dx][1], acc[g][1], 0, 0, 0);
          }
      }
    }
    int hr = h0 + r;
    #pragma unroll
    for (int g = 0; g < 2; g++)
      #pragma unroll
      for (int hf = 0; hf < 2; hf++) {
        int co = hf * 16 + (lane & 15);
        int pix0 = wv * 32 + g * 16 + ((lane >> 4) << 2);
        long idx = ((long)(b * 32 + co) * 128 + hr) * 128 + pix0;
        f32x4 xr = *reinterpret_cast<const f32x4*>(xres + idx);
        f32x4 o;
        #pragma unroll
        for (int j = 0; j < 4; j++) o[j] = acc[g][hf][j] + bco[hf] + xr[j];
        *reinterpret_cast<f32x4*>(outf + idx) = o;
      }
  }
}

extern "C" void kernel_launch(void* const* d_in, const int* in_sizes, int n_in,
                              void* d_out, int out_size, void* d_ws, size_t ws_size,
                              hipStream_t stream) {
  const float* x   = (const float*)d_in[0];
  const float* g1  = (const float*)d_in[1];
  const float* be1 = (const float*)d_in[2];
  const float* m1  = (const float*)d_in[3];
  const float* v1  = (const float*)d_in[4];
  const float* w1  = (const float*)d_in[5];
  const float* b1  = (const float*)d_in[6];
  const float* g2  = (const float*)d_in[7];
  const float* be2 = (const float*)d_in[8];
  const float* m2  = (const float*)d_in[9];
  const float* v2  = (const float*)d_in[10];
  const float* w2  = (const float*)d_in[11];
  const float* b2  = (const float*)d_in[12];

  char* ws = (char*)d_ws;
  unsigned short* hb = (unsigned short*)ws;                 // 64 MiB
  __bf16* wf1    = (__bf16*)(ws + 67108864);                // 18432 B
  __bf16* wf2    = (__bf16*)(ws + 67108864 + 18432);        // 18432 B
  float*  bias1p = (float*)(ws + 67108864 + 36864);         // 128 B
  float*  sc1    = (float*)(ws + 67108864 + 36992);         // 128 B
  float*  sf1    = (float*)(ws + 67108864 + 37120);         // 128 B

  prep_weights<<<dim3(72), dim3(256), 0, stream>>>(
      w1, b1, g2, be2, m2, v2, w2, g1, be1, m1, v1, wf1, wf2, bias1p, sc1, sf1);
  bnconv1<<<dim3(2048), dim3(256), 0, stream>>>(x, sc1, sf1, wf1, bias1p, hb);
  conv2_direct<<<dim3(2048), dim3(256), 0, stream>>>(hb, wf2, b2, x, (float*)d_out);
}

// Round 5
// 308.101 us; speedup vs baseline: 1.2692x; 1.0603x over previous
//
#include <hip/hip_runtime.h>

#define EPSV 1e-5f

typedef __bf16 bf16x8 __attribute__((ext_vector_type(8)));
typedef float f32x4 __attribute__((ext_vector_type(4)));
typedef float f32x2 __attribute__((ext_vector_type(2)));
typedef unsigned short ushort8 __attribute__((ext_vector_type(8)));

// ---------------- K0: weight fragments + folded biases + BN1 coeffs ----------------
// B-fragment layout for mfma_f32_16x16x32_bf16:
//   element (tap, half, lane, j) = w'[co = half*16 + (lane&15)][ci = (lane>>4)*8 + j][tap]
__global__ __launch_bounds__(256) void prep_weights(
    const float* __restrict__ w1, const float* __restrict__ b1,
    const float* __restrict__ g2, const float* __restrict__ be2,
    const float* __restrict__ m2, const float* __restrict__ v2,
    const float* __restrict__ w2,
    const float* __restrict__ g1, const float* __restrict__ be1,
    const float* __restrict__ m1, const float* __restrict__ v1,
    __bf16* __restrict__ wf1, __bf16* __restrict__ wf2,
    float* __restrict__ bias1p, float* __restrict__ sc1, float* __restrict__ sf1) {
  int i = blockIdx.x * 256 + threadIdx.x;   // 0..18431
  int conv = i / 9216;
  int rem  = i % 9216;
  int tap  = rem >> 10;          // 0..8
  int r2   = rem & 1023;
  int half = r2 >> 9;
  int lane = (r2 >> 3) & 63;
  int j    = r2 & 7;
  int ci = ((lane >> 4) << 3) + j;
  int co = half * 16 + (lane & 15);
  float val = (conv ? w2 : w1)[(co * 32 + ci) * 9 + tap];
  if (!conv) val *= g2[co] * rsqrtf(v2[co] + EPSV);   // fold BN2 scale into w1
  (conv ? wf2 : wf1)[rem] = (__bf16)val;
  if (blockIdx.x == 0 && threadIdx.x < 32) {
    int c = threadIdx.x;
    float s2 = g2[c] * rsqrtf(v2[c] + EPSV);
    bias1p[c] = s2 * b1[c] + (be2[c] - m2[c] * s2);   // scale2*b1 + shift2
  }
  if (blockIdx.x == 0 && threadIdx.x >= 64 && threadIdx.x < 96) {
    int c = threadIdx.x - 64;
    float s = g1[c] * rsqrtf(v1[c] + EPSV);
    sc1[c] = s;
    sf1[c] = be1[c] - m1[c] * s;
  }
}

// ---------------- K1: fully fused BN1+ReLU+conv1+BN2(folded)+ReLU+conv2+residual ----
// Block = 4-row output strip of one image. 8-slot LDS buffer, 8192 B/slot,
// layout [128 px][32 ch] bf16, chunk slot s = (ch>>3) ^ ((px>>1)&3).
// x row h0+k staged (BN1+ReLU, bf16) at slot k+2 (k=-2..5); h row h0+m (conv1 output,
// ReLU'd, BN2-scale folded into wf1) overwrites slot m+1 after its conv1 reads retire.
// conv2(r) reads h slots r..r+2; production of h r+2 reads x slots r+3..r+5 (disjoint)
// -> both run in one barrier segment. Edge columns via clamp+cndmask (no pad cols).
__global__ __launch_bounds__(256, 2) void fused_conv(
    const float* __restrict__ x,
    const float* __restrict__ sc1, const float* __restrict__ sf1,
    const __bf16* __restrict__ wf1, const __bf16* __restrict__ wf2,
    const float* __restrict__ bias1p, const float* __restrict__ b2,
    float* __restrict__ outf) {
  __shared__ __align__(16) unsigned short tile[8 * 4096];  // 65536 B exactly
  char* tb = reinterpret_cast<char*>(tile);
  int t = threadIdx.x, lane = t & 63, wv = t >> 6;
  int Bw = blockIdx.x;
  int logical = (Bw & 7) * 256 + (Bw >> 3);   // XCD-contiguous strips
  int b = logical >> 5, h0 = (logical & 31) * 4;

  // conv1 weights -> registers (72 VGPRs); conv2 weights stay in L1/L2 (global reads)
  bf16x8 Bf1[9][2];
  #pragma unroll
  for (int tap = 0; tap < 9; tap++)
    #pragma unroll
    for (int hf = 0; hf < 2; hf++)
      Bf1[tap][hf] = reinterpret_cast<const bf16x8*>(wf1)[(tap * 2 + hf) * 64 + lane];
  float bco1[2] = { bias1p[lane & 15], bias1p[16 + (lane & 15)] };
  float bco2[2] = { b2[lane & 15], b2[16 + (lane & 15)] };

  // per-lane A-fragment byte offsets within a slot + edge masks (shared by conv1/conv2)
  int cb = lane >> 4;
  int offs[2][3];
  bool bad[2][3];
  #pragma unroll
  for (int g = 0; g < 2; g++)
    #pragma unroll
    for (int dx = 0; dx < 3; dx++) {
      int w = wv * 32 + g * 16 + (lane & 15) + dx - 1;  // -1..128
      bad[g][dx] = (w < 0) || (w > 127);
      int wc = w < 0 ? 0 : (w > 127 ? 127 : w);
      offs[g][dx] = wc * 64 + ((cb ^ ((wc >> 1) & 3)) << 4);
    }

  // ---- stage 8 x rows (BN1+ReLU+pack); wave wv produces channel chunk wv ----
  float sc[8], sf[8];
  #pragma unroll
  for (int cc = 0; cc < 8; cc++) { sc[cc] = sc1[wv * 8 + cc]; sf[cc] = sf1[wv * 8 + cc]; }
  int wb0 = 128 * lane + ((wv ^ (lane & 3)) << 4);
  #pragma unroll
  for (int k = 0; k < 8; k++) {
    int hr = h0 - 2 + k;
    char* dst = tb + k * 8192 + wb0;
    if (hr >= 0 && hr < 128) {
      const float* src = x + (long)(b * 32 + wv * 8) * 16384 + hr * 128 + 2 * lane;
      float p0[8], p1[8];
      #pragma unroll
      for (int cc = 0; cc < 8; cc++) {
        f32x2 v = *reinterpret_cast<const f32x2*>(src + cc * 16384);
        p0[cc] = fmaxf(fmaf(v[0], sc[cc], sf[cc]), 0.0f);
        p1[cc] = fmaxf(fmaf(v[1], sc[cc], sf[cc]), 0.0f);
      }
      bf16x8 a0, a1;
      #pragma unroll
      for (int cc = 0; cc < 8; cc++) { a0[cc] = (__bf16)p0[cc]; a1[cc] = (__bf16)p1[cc]; }
      *reinterpret_cast<bf16x8*>(dst) = a0;
      *reinterpret_cast<bf16x8*>(dst + 64) = a1;
    } else {
      *reinterpret_cast<bf16x8*>(dst) = bf16x8{};
      *reinterpret_cast<bf16x8*>(dst + 64) = bf16x8{};
    }
  }
  __syncthreads();

  // ---- prologue: produce h rows m = -1, 0, 1 ----
  f32x4 ha[3][2][2] = {};
  #pragma unroll
  for (int m = -1; m <= 1; m++) {
    if (h0 + m >= 0) {           // only m=-1 at h0=0 can be OOB; upper edge impossible here
      #pragma unroll
      for (int dy = 0; dy < 3; dy++) {
        const char* rb = tb + (m + 1 + dy) * 8192;
        #pragma unroll
        for (int dx = 0; dx < 3; dx++)
          #pragma unroll
          for (int g = 0; g < 2; g++) {
            bf16x8 a = *reinterpret_cast<const bf16x8*>(rb + offs[g][dx]);
            if (bad[g][dx]) a = bf16x8{};
            ha[m + 1][g][0] = __builtin_amdgcn_mfma_f32_16x16x32_bf16(a, Bf1[dy * 3 + dx][0], ha[m + 1][g][0], 0, 0, 0);
            ha[m + 1][g][1] = __builtin_amdgcn_mfma_f32_16x16x32_bf16(a, Bf1[dy * 3 + dx][1], ha[m + 1][g][1], 0, 0, 0);
          }
      }
    }
  }
  __syncthreads();
  #pragma unroll
  for (int m = -1; m <= 1; m++) {
    if (h0 + m >= 0) {
      #pragma unroll
      for (int g = 0; g < 2; g++)
        #pragma unroll
        for (int hf = 0; hf < 2; hf++) {
          int co = hf * 16 + (lane & 15);
          #pragma unroll
          for (int j = 0; j < 4; j++) {
            int pix = wv * 32 + g * 16 + ((lane >> 4) << 2) + j;
            float val = fmaxf(ha[m + 1][g][hf][j] + bco1[hf], 0.0f);
            int byte = (m + 1) * 8192 + pix * 64 + (((co >> 3) ^ ((pix >> 1) & 3)) << 4) + (co & 7) * 2;
            *reinterpret_cast<unsigned short*>(tb + byte) =
                __builtin_bit_cast(unsigned short, (__bf16)val);
          }
        }
    } else {
      char* zb = tb + (m + 1) * 8192 + t * 32;
      *reinterpret_cast<ushort8*>(zb) = ushort8{};
      *reinterpret_cast<ushort8*>(zb + 16) = ushort8{};
    }
  }
  __syncthreads();

  // ---- steady state: r = 0..3 ----
  #pragma unroll
  for (int r = 0; r < 4; r++) {
    // conv2(r): reads h slots r..r+2; wf2 B-frags from global (L1-resident)
    f32x4 c2[2][2] = {};
    #pragma unroll
    for (int dy = 0; dy < 3; dy++) {
      const char* rb = tb + (r + dy) * 8192;
      #pragma unroll
      for (int dx = 0; dx < 3; dx++) {
        bf16x8 B0 = reinterpret_cast<const bf16x8*>(wf2)[((dy * 3 + dx) * 2 + 0) * 64 + lane];
        bf16x8 B1 = reinterpret_cast<const bf16x8*>(wf2)[((dy * 3 + dx) * 2 + 1) * 64 + lane];
        #pragma unroll
        for (int g = 0; g < 2; g++) {
          bf16x8 a = *reinterpret_cast<const bf16x8*>(rb + offs[g][dx]);
          if (bad[g][dx]) a = bf16x8{};
          c2[g][0] = __builtin_amdgcn_mfma_f32_16x16x32_bf16(a, B0, c2[g][0], 0, 0, 0);
          c2[g][1] = __builtin_amdgcn_mfma_f32_16x16x32_bf16(a, B1, c2[g][1], 0, 0, 0);
        }
      }
    }

    // production of h row r+2 (same segment: reads x slots r+3..r+5, disjoint from conv2)
    if (r < 3) {
      f32x4 hn[2][2] = {};
      bool inimg = (h0 + r + 2) < 128;    // lower bound always fine (>=2)
      if (inimg) {
        #pragma unroll
        for (int dy = 0; dy < 3; dy++) {
          const char* rb = tb + (r + 3 + dy) * 8192;
          #pragma unroll
          for (int dx = 0; dx < 3; dx++)
            #pragma unroll
            for (int g = 0; g < 2; g++) {
              bf16x8 a = *reinterpret_cast<const bf16x8*>(rb + offs[g][dx]);
              if (bad[g][dx]) a = bf16x8{};
              hn[g][0] = __builtin_amdgcn_mfma_f32_16x16x32_bf16(a, Bf1[dy * 3 + dx][0], hn[g][0], 0, 0, 0);
              hn[g][1] = __builtin_amdgcn_mfma_f32_16x16x32_bf16(a, Bf1[dy * 3 + dx][1], hn[g][1], 0, 0, 0);
            }
        }
      }
      // conv2 epilogue (independent of production; global ops overlap the barrier wait)
      {
        int hr = h0 + r;
        #pragma unroll
        for (int g = 0; g < 2; g++)
          #pragma unroll
          for (int hf = 0; hf < 2; hf++) {
            int co = hf * 16 + (lane & 15);
            int pix0 = wv * 32 + g * 16 + ((lane >> 4) << 2);
            long idx = ((long)(b * 32 + co) * 128 + hr) * 128 + pix0;
            f32x4 xr = *reinterpret_cast<const f32x4*>(x + idx);
            f32x4 o;
            #pragma unroll
            for (int j = 0; j < 4; j++) o[j] = c2[g][hf][j] + bco2[hf] + xr[j];
            *reinterpret_cast<f32x4*>(outf + idx) = o;
          }
      }
      __syncthreads();   // all conv1/conv2 reads of slot r+3 done
      if (inimg) {
        #pragma unroll
        for (int g = 0; g < 2; g++)
          #pragma unroll
          for (int hf = 0; hf < 2; hf++) {
            int co = hf * 16 + (lane & 15);
            #pragma unroll
            for (int j = 0; j < 4; j++) {
              int pix = wv * 32 + g * 16 + ((lane >> 4) << 2) + j;
              float val = fmaxf(hn[g][hf][j] + bco1[hf], 0.0f);
              int byte = (r + 3) * 8192 + pix * 64 + (((co >> 3) ^ ((pix >> 1) & 3)) << 4) + (co & 7) * 2;
              *reinterpret_cast<unsigned short*>(tb + byte) =
                  __builtin_bit_cast(unsigned short, (__bf16)val);
            }
          }
      } else {
        char* zb = tb + (r + 3) * 8192 + t * 32;
        *reinterpret_cast<ushort8*>(zb) = ushort8{};
        *reinterpret_cast<ushort8*>(zb + 16) = ushort8{};
      }
      __syncthreads();   // slot r+3 (h row r+2) visible for conv2(r+1)
    } else {
      int hr = h0 + r;
      #pragma unroll
      for (int g = 0; g < 2; g++)
        #pragma unroll
        for (int hf = 0; hf < 2; hf++) {
          int co = hf * 16 + (lane & 15);
          int pix0 = wv * 32 + g * 16 + ((lane >> 4) << 2);
          long idx = ((long)(b * 32 + co) * 128 + hr) * 128 + pix0;
          f32x4 xr = *reinterpret_cast<const f32x4*>(x + idx);
          f32x4 o;
          #pragma unroll
          for (int j = 0; j < 4; j++) o[j] = c2[g][hf][j] + bco2[hf] + xr[j];
          *reinterpret_cast<f32x4*>(outf + idx) = o;
        }
    }
  }
}

extern "C" void kernel_launch(void* const* d_in, const int* in_sizes, int n_in,
                              void* d_out, int out_size, void* d_ws, size_t ws_size,
                              hipStream_t stream) {
  const float* x   = (const float*)d_in[0];
  const float* g1  = (const float*)d_in[1];
  const float* be1 = (const float*)d_in[2];
  const float* m1  = (const float*)d_in[3];
  const float* v1  = (const float*)d_in[4];
  const float* w1  = (const float*)d_in[5];
  const float* b1  = (const float*)d_in[6];
  const float* g2  = (const float*)d_in[7];
  const float* be2 = (const float*)d_in[8];
  const float* m2  = (const float*)d_in[9];
  const float* v2  = (const float*)d_in[10];
  const float* w2  = (const float*)d_in[11];
  const float* b2  = (const float*)d_in[12];

  char* ws = (char*)d_ws;
  __bf16* wf1    = (__bf16*)ws;                  // 18432 B
  __bf16* wf2    = (__bf16*)(ws + 18432);        // 18432 B
  float*  bias1p = (float*)(ws + 36864);         // 128 B
  float*  sc1    = (float*)(ws + 36992);         // 128 B
  float*  sf1    = (float*)(ws + 37120);         // 128 B

  prep_weights<<<dim3(72), dim3(256), 0, stream>>>(
      w1, b1, g2, be2, m2, v2, w2, g1, be1, m1, v1, wf1, wf2, bias1p, sc1, sf1);
  fused_conv<<<dim3(2048), dim3(256), 0, stream>>>(
      x, sc1, sf1, wf1, wf2, bias1p, b2, (float*)d_out);
}